// Round 3
// baseline (492.110 us; speedup 1.0000x reference)
//
#include <hip/hip_runtime.h>
#include <math.h>

// Problem dims (fixed by setup_inputs): inp [1,2,48,160,160] f32, target [1,48,160,160] i32
#define D_ 48
#define H_ 160
#define W_ 160
#define HW_ 25600
#define N_ 1228800
#define NBLK 4800          // N_/256
#define HBLK 600           // 8 elems/thread passes
#define K1_ 1216512u       // 1-based rank of sorted index floor(0.99*(N-1)); frac==0 in f32 (R1: absmax 0.0)

static_assert(N_ == D_ * HW_, "dims");
static_assert(N_ == NBLK * 256, "grid");
static_assert(N_ == HBLK * 256 * 8, "hist grid");

// ---- workspace layout (bytes) ----
#define OFF_KL   0u
#define OFF_FA   (N_ * 4u)
#define OFF_FB   (2u * N_ * 4u)
#define OFF_CAND (3u * N_ * 4u)            // worst-case capacity: all N values in one bucket
#define OFF_G1   (4u * N_ * 4u)            // 4096 u32
#define OFF_SC   (OFF_G1 + 4096u * 4u)     // 16 u32 scalars
#define OFF_PS   (OFF_SC + 64u)
#define OFF_PC   (OFF_PS + NBLK * 4u)
// sc: [0]=b1 [1]=rank-in-bucket [6]=thr bits [8]=candCount [9]=ctrCompact [10]=ctrLoss

__device__ __forceinline__ unsigned fkey(float v) {
  unsigned u = __float_as_uint(v);
  return (u & 0x80000000u) ? ~u : (u | 0x80000000u);  // monotone map: float asc -> uint asc
}

// ---------------- zero g1 + scalars (replaces the 40us hipMemsetAsync) ----------------
__global__ __launch_bounds__(256) void k_zero(unsigned* __restrict__ g1,
                                              unsigned* __restrict__ sc) {
  const int i = blockIdx.x * 256 + threadIdx.x;
  if (i < 4096) g1[i] = 0u;
  else if (i < 4112) sc[i - 4096] = 0u;
}

// ---------------- kl_vals + initial dist field + level-1 (hi-12) histogram ----------------
__global__ __launch_bounds__(256) void k_prep(const float* __restrict__ inp,
                                              const int* __restrict__ tgt,
                                              float* __restrict__ kl,
                                              float* __restrict__ f0,
                                              unsigned* __restrict__ ghist) {
  __shared__ unsigned h[4096];
  const int tid = threadIdx.x;
  for (int i = tid; i < 4096; i += 256) h[i] = 0;
  __syncthreads();
  const int base = blockIdx.x * 2048;
  for (int e = 0; e < 8; e++) {
    const int idx = base + e * 256 + tid;
    const int ww = idx % W_;
    const int hh = (idx / W_) % H_;
    const int dd = idx / HW_;
    const float p0 = inp[idx];
    const float p1 = inp[N_ + idx];

    float klh = -1.0f, klv = -1.0f, kld = -1.0f;
    if (ww < W_ - 1) {
      const float t0 = inp[idx + 1], t1 = inp[N_ + idx + 1];
      const float a0 = (t0 > 0.f) ? t0 * logf(t0) : 0.f;
      const float a1 = (t1 > 0.f) ? t1 * logf(t1) : 0.f;
      klh = 0.5f * ((a0 - t0 * p0) + (a1 - t1 * p1));
    }
    if (hh < H_ - 1) {
      const float t0 = inp[idx + W_], t1 = inp[N_ + idx + W_];
      const float a0 = (t0 > 0.f) ? t0 * logf(t0) : 0.f;
      const float a1 = (t1 > 0.f) ? t1 * logf(t1) : 0.f;
      klv = 0.5f * ((a0 - t0 * p0) + (a1 - t1 * p1));
    }
    if (dd < D_ - 1) {
      const float t0 = inp[idx + HW_], t1 = inp[N_ + idx + HW_];
      const float a0 = (t0 > 0.f) ? t0 * logf(t0) : 0.f;
      const float a1 = (t1 > 0.f) ? t1 * logf(t1) : 0.f;
      kld = 0.5f * ((a0 - t0 * p0) + (a1 - t1 * p1));
    }
    const float kmax = fmaxf(fmaxf(klh, klv), kld);
    kl[idx] = kmax;
    atomicAdd(&h[fkey(kmax) >> 20], 1u);

    const int tv = tgt[idx];
    const int t1 = (ww < W_ - 1) ? tgt[idx + 1] : 0;
    const int t2 = (hh < H_ - 1) ? tgt[idx + W_] : 0;
    const int t3 = (dd < D_ - 1) ? tgt[idx + HW_] : 0;
    f0[idx] = (3 * tv != t1 + t2 + t3) ? 0.f : 1e10f;
  }
  __syncthreads();
  for (int i = tid; i < 4096; i += 256) {
    const unsigned c = h[i];
    if (c) atomicAdd(&ghist[i], c);
  }
}

// ---------------- EDT pass along one axis, early-exit outward scan (bit-exact) ----------------
// Since f>=0, RN(f[j]+r^2) >= r^2, so once r^2 >= m no candidate can lower the min; min over
// a set is order-independent -> identical bits vs brute force.
template <int STRIDE, int LEN, int AXIS>
__global__ __launch_bounds__(256) void k_dt(const float* __restrict__ fin,
                                            float* __restrict__ fout) {
  const int idx = blockIdx.x * 256 + threadIdx.x;
  const int pos = (AXIS == 0) ? (idx / HW_) : ((idx / W_) % H_);
  float m = fin[idx];
  for (int r = 1; r < LEN; r++) {
    const float r2 = (float)(r * r);
    if (r2 >= m) break;
    const int jm = pos - r, jp = pos + r;
    const bool okm = (jm >= 0), okp = (jp < LEN);
    if (!okm && !okp) break;
    if (okm) m = fminf(m, fin[idx - r * STRIDE] + r2);
    if (okp) m = fminf(m, fin[idx + r * STRIDE] + r2);
  }
  fout[idx] = m;
}

// ---------------- last EDT pass (W axis) + sqrt, with level-1 rank-select folded into block 0 ----------------
__global__ __launch_bounds__(256) void k_dt_w(const float* __restrict__ fin,
                                              float* __restrict__ fout,
                                              const unsigned* __restrict__ g1,
                                              unsigned* __restrict__ sc) {
  const int idx = blockIdx.x * 256 + threadIdx.x;
  const int pos = idx % W_;
  float m = fin[idx];
  for (int r = 1; r < W_; r++) {
    const float r2 = (float)(r * r);
    if (r2 >= m) break;
    const int jm = pos - r, jp = pos + r;
    const bool okm = (jm >= 0), okp = (jp < W_);
    if (!okm && !okp) break;
    if (okm) m = fminf(m, fin[idx - r] + r2);
    if (okp) m = fminf(m, fin[idx + r] + r2);
  }
  fout[idx] = sqrtf(m);

  // block 0: select hi-12 bucket containing rank K1_ (depends only on g1, done 2 kernels ago)
  if (blockIdx.x == 0) {
    __shared__ unsigned ssum[256];
    __shared__ unsigned spre[256];
    const int t = threadIdx.x;
    unsigned s = 0;
#pragma unroll
    for (int i = 0; i < 16; i++) s += g1[t * 16 + i];
    ssum[t] = s;
    __syncthreads();
    if (t == 0) {
      unsigned c = 0;
      for (int i = 0; i < 256; i++) { spre[i] = c; c += ssum[i]; }
    }
    __syncthreads();
    const unsigned before = spre[t];
    if (before < K1_ && K1_ <= before + ssum[t]) {
      unsigned cum = before;
      for (int i = 0; i < 16; i++) {
        const unsigned c = g1[t * 16 + i];
        if (cum < K1_ && K1_ <= cum + c) { sc[0] = (unsigned)(t * 16 + i); sc[1] = K1_ - cum; break; }
        cum += c;
      }
    }
  }
}

// ---------------- compact bucket-b1 values; last block does the 12+8 radix select ----------------
__global__ __launch_bounds__(256) void k_compact(const float* __restrict__ kl,
                                                 unsigned* __restrict__ cand,
                                                 unsigned* __restrict__ sc) {
  const int tid = threadIdx.x;
  const unsigned b1 = sc[0];
  const int base = blockIdx.x * 2048;
  for (int e = 0; e < 8; e++) {
    const int idx = base + e * 256 + tid;
    const unsigned key = fkey(kl[idx]);
    if ((key >> 20) == b1) {
      const unsigned pos = atomicAdd(&sc[8], 1u);
      __hip_atomic_store(&cand[pos], key & 0xFFFFFu, __ATOMIC_RELAXED, __HIP_MEMORY_SCOPE_AGENT);
    }
  }
  __syncthreads();
  __threadfence();
  __shared__ int isLast;
  if (tid == 0) isLast = (atomicAdd(&sc[9], 1u) == HBLK - 1) ? 1 : 0;
  __syncthreads();
  if (!isLast) return;
  __threadfence();

  // --- winning block: exact rank-select over the compacted set (order-independent) ---
  const unsigned M = __hip_atomic_load(&sc[8], __ATOMIC_RELAXED, __HIP_MEMORY_SCOPE_AGENT);
  const unsigned K = sc[1];
  __shared__ unsigned hist[4096];
  __shared__ unsigned ssum[256];
  __shared__ unsigned spre[256];
  __shared__ unsigned sBA, sKB;
  for (int i = tid; i < 4096; i += 256) hist[i] = 0;
  __syncthreads();
  for (unsigned i = tid; i < M; i += 256) {
    const unsigned v = __hip_atomic_load(&cand[i], __ATOMIC_RELAXED, __HIP_MEMORY_SCOPE_AGENT);
    atomicAdd(&hist[(v >> 8) & 0xFFFu], 1u);
  }
  __syncthreads();
  {
    unsigned s = 0;
#pragma unroll
    for (int i = 0; i < 16; i++) s += hist[tid * 16 + i];
    ssum[tid] = s;
  }
  __syncthreads();
  if (tid == 0) {
    unsigned c = 0;
    for (int i = 0; i < 256; i++) { spre[i] = c; c += ssum[i]; }
  }
  __syncthreads();
  {
    const unsigned before = spre[tid];
    if (before < K && K <= before + ssum[tid]) {
      unsigned cum = before;
      for (int i = 0; i < 16; i++) {
        const unsigned c = hist[tid * 16 + i];
        if (cum < K && K <= cum + c) { sBA = (unsigned)(tid * 16 + i); sKB = K - cum; break; }
        cum += c;
      }
    }
  }
  __syncthreads();
  const unsigned bA = sBA, KB = sKB;
  __shared__ unsigned h2[256];
  h2[tid] = 0;
  __syncthreads();
  for (unsigned i = tid; i < M; i += 256) {
    const unsigned v = __hip_atomic_load(&cand[i], __ATOMIC_RELAXED, __HIP_MEMORY_SCOPE_AGENT);
    if (((v >> 8) & 0xFFFu) == bA) atomicAdd(&h2[v & 0xFFu], 1u);
  }
  __syncthreads();
  ssum[tid] = h2[tid];
  __syncthreads();
  if (tid == 0) {
    unsigned c = 0;
    for (int i = 0; i < 256; i++) { spre[i] = c; c += ssum[i]; }
  }
  __syncthreads();
  {
    const unsigned before = spre[tid];
    if (before < KB && KB <= before + h2[tid]) {
      const unsigned key = (sc[0] << 20) | (bA << 8) | (unsigned)tid;
      sc[6] = (key & 0x80000000u) ? (key & 0x7FFFFFFFu) : ~key;  // inverse of fkey
    }
  }
}

// ---------------- masked loss + block partials + last-block deterministic reduce ----------------
__global__ __launch_bounds__(256) void k_loss(const float* __restrict__ inp,
                                              const float* __restrict__ kl,
                                              const float* __restrict__ gdist,
                                              unsigned* __restrict__ sc,
                                              float* __restrict__ psum,
                                              unsigned* __restrict__ pcnt,
                                              float* __restrict__ out) {
  const int tid = threadIdx.x;
  const int idx = blockIdx.x * 256 + tid;
  const float thr = __uint_as_float(sc[6]);
  float myloss = 0.f;
  unsigned mycnt = 0u;
  if (kl[idx] >= thr) {
    mycnt = 1u;
    const float g = gdist[idx];
    if (g != 0.f) {
      const int ww = idx % W_;
      const int hh = (idx / W_) % H_;
      const int dd = idx / HW_;
      const float p0 = inp[idx];
      const float p1 = inp[N_ + idx];
      // DIRECTIONS in torch-loop order: i outer, j mid, k inner, skipping (0,0,0)
      constexpr int DI[26] = {-1,-1,-1,-1,-1,-1,-1,-1,-1, 0,0,0,0,0,0,0,0, 1,1,1,1,1,1,1,1,1};
      constexpr int DJ[26] = {-1,-1,-1, 0,0,0, 1,1,1, -1,-1,-1, 0,0, 1,1,1, -1,-1,-1, 0,0,0, 1,1,1};
      constexpr int DK[26] = {-1,0,1, -1,0,1, -1,0,1, -1,0,1, -1,1, -1,0,1, -1,0,1, -1,0,1, -1,0,1};
      float klv[26], dst[26];
      float s = 0.f;
#pragma unroll
      for (int t = 0; t < 26; t++) {
        const int nd = dd + DI[t], nh = hh + DJ[t], nw = ww + DK[t];
        const bool inb = ((unsigned)nd < (unsigned)D_) && ((unsigned)nh < (unsigned)H_) &&
                         ((unsigned)nw < (unsigned)W_);
        const int nidx = (nd * H_ + nh) * W_ + nw;
        dst[t] = inb ? gdist[nidx] : 0.f;
        // coordinate masks from the reference's (batch,d,h) indexing bug, specialized to B=1:
        //  i==+1 -> 0; j==+1 -> 0; j==-1 -> only d==0; k==+1 -> only h==159; k==-1 -> only h==0
        bool keep;
        if (DI[t] == 1 || DJ[t] == 1) keep = false;
        else {
          keep = true;
          if (DJ[t] == -1) keep = (dd == 0);
          if (DK[t] == 1) keep = keep && (hh == H_ - 1);
          if (DK[t] == -1) keep = keep && (hh == 0);
        }
        float kt = 0.f;
        if (keep) {
          float t0 = 0.f, t1 = 0.f;
          if (inb) { t0 = inp[nidx]; t1 = inp[N_ + nidx]; }
          const float a0 = (t0 > 0.f) ? t0 * logf(t0) : 0.f;
          const float a1 = (t1 > 0.f) ? t1 * logf(t1) : 0.f;
          const float kldm = 0.5f * ((a0 - t0 * p0) + (a1 - t1 * p1));
          kt = expf(kldm);
        }
        klv[t] = kt;
        s += kt;
      }
      const float denom = (s == 0.f) ? 1.f : s;
      int amin = 0;
      float dmin = dst[0];
#pragma unroll
      for (int t = 1; t < 26; t++) {
        if (dst[t] < dmin) { dmin = dst[t]; amin = t; }  // first-min, like jnp.argmin
      }
      const float yoff = (float)(0.2 / 26.0);
      float bsum = 0.f;
#pragma unroll
      for (int t = 0; t < 26; t++) {
        const float x = klv[t] / denom;
        const float y = (t == amin) ? 0.8f : yoff;
        bsum += fmaxf(x, 0.f) - x * y + log1pf(expf(-fabsf(x)));
      }
      myloss = (fminf(g, 20.f) / 20.f) * (bsum / 26.f);
    }
  }
  __shared__ float ls[256];
  __shared__ unsigned lc[256];
  ls[tid] = myloss;
  lc[tid] = mycnt;
  __syncthreads();
  for (int o = 128; o > 0; o >>= 1) {
    if (tid < o) { ls[tid] += ls[tid + o]; lc[tid] += lc[tid + o]; }
    __syncthreads();
  }
  if (tid == 0) {
    __hip_atomic_store(&psum[blockIdx.x], ls[0], __ATOMIC_RELAXED, __HIP_MEMORY_SCOPE_AGENT);
    __hip_atomic_store(&pcnt[blockIdx.x], lc[0], __ATOMIC_RELAXED, __HIP_MEMORY_SCOPE_AGENT);
  }
  __threadfence();
  __shared__ int isLast;
  if (tid == 0) isLast = (atomicAdd(&sc[10], 1u) == NBLK - 1) ? 1 : 0;
  __syncthreads();
  if (!isLast) return;
  __threadfence();
  // winning block: fixed-order reduction (strided + tree) -> deterministic result
  float s2 = 0.f;
  unsigned c2 = 0;
  for (int i = tid; i < NBLK; i += 256) {
    s2 += __hip_atomic_load(&psum[i], __ATOMIC_RELAXED, __HIP_MEMORY_SCOPE_AGENT);
    c2 += __hip_atomic_load(&pcnt[i], __ATOMIC_RELAXED, __HIP_MEMORY_SCOPE_AGENT);
  }
  __syncthreads();
  ls[tid] = s2;
  lc[tid] = c2;
  __syncthreads();
  for (int o = 128; o > 0; o >>= 1) {
    if (tid < o) { ls[tid] += ls[tid + o]; lc[tid] += lc[tid + o]; }
    __syncthreads();
  }
  if (tid == 0) out[0] = ls[0] / (float)lc[0];
}

extern "C" void kernel_launch(void* const* d_in, const int* in_sizes, int n_in,
                              void* d_out, int out_size, void* d_ws, size_t ws_size,
                              hipStream_t stream) {
  (void)in_sizes; (void)n_in; (void)out_size; (void)ws_size;
  const float* inp = (const float*)d_in[0];
  const int* tgt = (const int*)d_in[1];
  float* out = (float*)d_out;
  char* ws = (char*)d_ws;

  float* kl = (float*)(ws + OFF_KL);
  float* fA = (float*)(ws + OFF_FA);
  float* fB = (float*)(ws + OFF_FB);
  unsigned* cand = (unsigned*)(ws + OFF_CAND);
  unsigned* g1 = (unsigned*)(ws + OFF_G1);
  unsigned* sc = (unsigned*)(ws + OFF_SC);
  float* ps = (float*)(ws + OFF_PS);
  unsigned* pc = (unsigned*)(ws + OFF_PC);

  k_zero<<<17, 256, 0, stream>>>(g1, sc);
  k_prep<<<HBLK, 256, 0, stream>>>(inp, tgt, kl, fA, g1);
  k_dt<HW_, D_, 0><<<NBLK, 256, 0, stream>>>(fA, fB);   // EDT axis D (reference order)
  k_dt<W_, H_, 1><<<NBLK, 256, 0, stream>>>(fB, fA);    // EDT axis H
  k_dt_w<<<NBLK, 256, 0, stream>>>(fA, fB, g1, sc);     // EDT axis W + sqrt + sel1 in block 0
  k_compact<<<HBLK, 256, 0, stream>>>(kl, cand, sc);    // compact bucket + last-block radix select
  k_loss<<<NBLK, 256, 0, stream>>>(inp, kl, fB, sc, ps, pc, out);  // loss + last-block reduce
}

// Round 4
// 114.674 us; speedup vs baseline: 4.2914x; 4.2914x over previous
//
#include <hip/hip_runtime.h>
#include <math.h>

// Problem dims (fixed by setup_inputs): inp [1,2,48,160,160] f32, target [1,48,160,160] i32
#define D_ 48
#define H_ 160
#define W_ 160
#define HW_ 25600
#define N_ 1228800
#define NBLK 4800          // N_/256
#define HBLK 600           // 8 elems/thread passes
#define K1_ 1216512u       // 1-based rank of sorted index floor(0.99*(N-1)); frac==0 in f32 (R1: absmax 0.0)

static_assert(N_ == D_ * HW_, "dims");
static_assert(N_ == NBLK * 256, "grid");
static_assert(N_ == HBLK * 256 * 8, "hist grid");

// ---- workspace layout (bytes) ----
#define OFF_KL   0u
#define OFF_FA   (N_ * 4u)
#define OFF_FB   (2u * N_ * 4u)
#define OFF_CAND (3u * N_ * 4u)            // worst-case capacity: all N values in one bucket
#define OFF_G1   (4u * N_ * 4u)            // 4096 u32
#define OFF_SC   (OFF_G1 + 4096u * 4u)     // 16 u32 scalars
#define OFF_PS   (OFF_SC + 64u)
#define OFF_PC   (OFF_PS + NBLK * 4u)
// sc: [0]=b1 [1]=rank-in-bucket [6]=thr bits [8]=candCount

__device__ __forceinline__ unsigned fkey(float v) {
  unsigned u = __float_as_uint(v);
  return (u & 0x80000000u) ? ~u : (u | 0x80000000u);  // monotone map: float asc -> uint asc
}

// ---------------- zero g1 + scalars (replaces the 40us hipMemsetAsync) ----------------
__global__ __launch_bounds__(256) void k_zero(unsigned* __restrict__ g1,
                                              unsigned* __restrict__ sc) {
  const int i = blockIdx.x * 256 + threadIdx.x;
  if (i < 4096) g1[i] = 0u;
  else if (i < 4112) sc[i - 4096] = 0u;
}

// ---------------- kl_vals + initial dist field + level-1 (hi-12) histogram ----------------
__global__ __launch_bounds__(256) void k_prep(const float* __restrict__ inp,
                                              const int* __restrict__ tgt,
                                              float* __restrict__ kl,
                                              float* __restrict__ f0,
                                              unsigned* __restrict__ ghist) {
  __shared__ unsigned h[4096];
  const int tid = threadIdx.x;
  for (int i = tid; i < 4096; i += 256) h[i] = 0;
  __syncthreads();
  const int base = blockIdx.x * 2048;
  for (int e = 0; e < 8; e++) {
    const int idx = base + e * 256 + tid;
    const int ww = idx % W_;
    const int hh = (idx / W_) % H_;
    const int dd = idx / HW_;
    const float p0 = inp[idx];
    const float p1 = inp[N_ + idx];

    float klh = -1.0f, klv = -1.0f, kld = -1.0f;
    if (ww < W_ - 1) {
      const float t0 = inp[idx + 1], t1 = inp[N_ + idx + 1];
      const float a0 = (t0 > 0.f) ? t0 * logf(t0) : 0.f;
      const float a1 = (t1 > 0.f) ? t1 * logf(t1) : 0.f;
      klh = 0.5f * ((a0 - t0 * p0) + (a1 - t1 * p1));
    }
    if (hh < H_ - 1) {
      const float t0 = inp[idx + W_], t1 = inp[N_ + idx + W_];
      const float a0 = (t0 > 0.f) ? t0 * logf(t0) : 0.f;
      const float a1 = (t1 > 0.f) ? t1 * logf(t1) : 0.f;
      klv = 0.5f * ((a0 - t0 * p0) + (a1 - t1 * p1));
    }
    if (dd < D_ - 1) {
      const float t0 = inp[idx + HW_], t1 = inp[N_ + idx + HW_];
      const float a0 = (t0 > 0.f) ? t0 * logf(t0) : 0.f;
      const float a1 = (t1 > 0.f) ? t1 * logf(t1) : 0.f;
      kld = 0.5f * ((a0 - t0 * p0) + (a1 - t1 * p1));
    }
    const float kmax = fmaxf(fmaxf(klh, klv), kld);
    kl[idx] = kmax;
    atomicAdd(&h[fkey(kmax) >> 20], 1u);

    const int tv = tgt[idx];
    const int t1 = (ww < W_ - 1) ? tgt[idx + 1] : 0;
    const int t2 = (hh < H_ - 1) ? tgt[idx + W_] : 0;
    const int t3 = (dd < D_ - 1) ? tgt[idx + HW_] : 0;
    f0[idx] = (3 * tv != t1 + t2 + t3) ? 0.f : 1e10f;
  }
  __syncthreads();
  for (int i = tid; i < 4096; i += 256) {
    const unsigned c = h[i];
    if (c) atomicAdd(&ghist[i], c);
  }
}

// ---------------- EDT pass along D, early-exit outward scan (bit-exact vs brute force) ----------------
// Since f>=0, RN(f[j]+r^2) >= r^2, so once r^2 >= m no candidate can lower the min; min over
// a set is order-independent -> identical bits vs brute force.
__global__ __launch_bounds__(256) void k_dt_d(const float* __restrict__ fin,
                                              float* __restrict__ fout) {
  const int idx = blockIdx.x * 256 + threadIdx.x;
  const int pos = idx / HW_;
  float m = fin[idx];
  for (int r = 1; r < D_; r++) {
    const float r2 = (float)(r * r);
    if (r2 >= m) break;
    const bool okm = (pos - r >= 0), okp = (pos + r < D_);
    if (!okm && !okp) break;
    if (okm) m = fminf(m, fin[idx - r * HW_] + r2);
    if (okp) m = fminf(m, fin[idx + r * HW_] + r2);
  }
  fout[idx] = m;
}

// ---------------- EDT pass along H + level-1 rank-select in block 0 (g1 boundary-synced) ----------------
__global__ __launch_bounds__(256) void k_dt_h(const float* __restrict__ fin,
                                              float* __restrict__ fout,
                                              const unsigned* __restrict__ g1,
                                              unsigned* __restrict__ sc) {
  const int idx = blockIdx.x * 256 + threadIdx.x;
  const int pos = (idx / W_) % H_;
  float m = fin[idx];
  for (int r = 1; r < H_; r++) {
    const float r2 = (float)(r * r);
    if (r2 >= m) break;
    const bool okm = (pos - r >= 0), okp = (pos + r < H_);
    if (!okm && !okp) break;
    if (okm) m = fminf(m, fin[idx - r * W_] + r2);
    if (okp) m = fminf(m, fin[idx + r * W_] + r2);
  }
  fout[idx] = m;

  if (blockIdx.x == 0) {
    __shared__ unsigned ssum[256];
    __shared__ unsigned spre[256];
    const int t = threadIdx.x;
    unsigned s = 0;
#pragma unroll
    for (int i = 0; i < 16; i++) s += g1[t * 16 + i];
    ssum[t] = s;
    __syncthreads();
    if (t == 0) {
      unsigned c = 0;
      for (int i = 0; i < 256; i++) { spre[i] = c; c += ssum[i]; }
    }
    __syncthreads();
    const unsigned before = spre[t];
    if (before < K1_ && K1_ <= before + ssum[t]) {
      unsigned cum = before;
      for (int i = 0; i < 16; i++) {
        const unsigned c = g1[t * 16 + i];
        if (cum < K1_ && K1_ <= cum + c) { sc[0] = (unsigned)(t * 16 + i); sc[1] = K1_ - cum; break; }
        cum += c;
      }
    }
  }
}

// ---------------- EDT pass along W + sqrt + bucket-b1 compaction (sc[0] boundary-synced) ----------------
__global__ __launch_bounds__(256) void k_dt_w(const float* __restrict__ fin,
                                              float* __restrict__ fout,
                                              const float* __restrict__ kl,
                                              unsigned* __restrict__ cand,
                                              unsigned* __restrict__ sc) {
  const int idx = blockIdx.x * 256 + threadIdx.x;
  const int pos = idx % W_;
  float m = fin[idx];
  for (int r = 1; r < W_; r++) {
    const float r2 = (float)(r * r);
    if (r2 >= m) break;
    const bool okm = (pos - r >= 0), okp = (pos + r < W_);
    if (!okm && !okp) break;
    if (okm) m = fminf(m, fin[idx - r] + r2);
    if (okp) m = fminf(m, fin[idx + r] + r2);
  }
  fout[idx] = sqrtf(m);

  // compact: keys in the selected hi-12 bucket (rare -> low atomic traffic). Order of
  // appends is nondeterministic; the downstream rank-select is order-independent.
  const unsigned key = fkey(kl[idx]);
  if ((key >> 20) == sc[0]) {
    const unsigned pos2 = atomicAdd(&sc[8], 1u);
    cand[pos2] = key & 0xFFFFFu;
  }
}

// ---------------- 12+8 radix select over the compacted candidates (1 block) ----------------
__global__ __launch_bounds__(256) void k_sel23(const unsigned* __restrict__ cand,
                                               unsigned* __restrict__ sc) {
  const int tid = threadIdx.x;
  const unsigned M = sc[8];
  const unsigned K = sc[1];
  __shared__ unsigned hist[4096];
  __shared__ unsigned ssum[256];
  __shared__ unsigned spre[256];
  __shared__ unsigned sBA, sKB;
  for (int i = tid; i < 4096; i += 256) hist[i] = 0;
  __syncthreads();
  for (unsigned i = tid; i < M; i += 256) atomicAdd(&hist[(cand[i] >> 8) & 0xFFFu], 1u);
  __syncthreads();
  {
    unsigned s = 0;
#pragma unroll
    for (int i = 0; i < 16; i++) s += hist[tid * 16 + i];
    ssum[tid] = s;
  }
  __syncthreads();
  if (tid == 0) {
    unsigned c = 0;
    for (int i = 0; i < 256; i++) { spre[i] = c; c += ssum[i]; }
  }
  __syncthreads();
  {
    const unsigned before = spre[tid];
    if (before < K && K <= before + ssum[tid]) {
      unsigned cum = before;
      for (int i = 0; i < 16; i++) {
        const unsigned c = hist[tid * 16 + i];
        if (cum < K && K <= cum + c) { sBA = (unsigned)(tid * 16 + i); sKB = K - cum; break; }
        cum += c;
      }
    }
  }
  __syncthreads();
  const unsigned bA = sBA, KB = sKB;
  __shared__ unsigned h2[256];
  h2[tid] = 0;
  __syncthreads();
  for (unsigned i = tid; i < M; i += 256) {
    const unsigned v = cand[i];
    if (((v >> 8) & 0xFFFu) == bA) atomicAdd(&h2[v & 0xFFu], 1u);
  }
  __syncthreads();
  ssum[tid] = h2[tid];
  __syncthreads();
  if (tid == 0) {
    unsigned c = 0;
    for (int i = 0; i < 256; i++) { spre[i] = c; c += ssum[i]; }
  }
  __syncthreads();
  {
    const unsigned before = spre[tid];
    if (before < KB && KB <= before + h2[tid]) {
      const unsigned key = (sc[0] << 20) | (bA << 8) | (unsigned)tid;
      sc[6] = (key & 0x80000000u) ? (key & 0x7FFFFFFFu) : ~key;  // inverse of fkey
    }
  }
}

// ---------------- masked loss at each voxel + block partials (plain stores) ----------------
__global__ __launch_bounds__(256) void k_loss(const float* __restrict__ inp,
                                              const float* __restrict__ kl,
                                              const float* __restrict__ gdist,
                                              const unsigned* __restrict__ sc,
                                              float* __restrict__ psum,
                                              unsigned* __restrict__ pcnt) {
  const int tid = threadIdx.x;
  const int idx = blockIdx.x * 256 + tid;
  const float thr = __uint_as_float(sc[6]);
  float myloss = 0.f;
  unsigned mycnt = 0u;
  if (kl[idx] >= thr) {
    mycnt = 1u;
    const float g = gdist[idx];
    if (g != 0.f) {
      const int ww = idx % W_;
      const int hh = (idx / W_) % H_;
      const int dd = idx / HW_;
      const float p0 = inp[idx];
      const float p1 = inp[N_ + idx];
      // DIRECTIONS in torch-loop order: i outer, j mid, k inner, skipping (0,0,0)
      constexpr int DI[26] = {-1,-1,-1,-1,-1,-1,-1,-1,-1, 0,0,0,0,0,0,0,0, 1,1,1,1,1,1,1,1,1};
      constexpr int DJ[26] = {-1,-1,-1, 0,0,0, 1,1,1, -1,-1,-1, 0,0, 1,1,1, -1,-1,-1, 0,0,0, 1,1,1};
      constexpr int DK[26] = {-1,0,1, -1,0,1, -1,0,1, -1,0,1, -1,1, -1,0,1, -1,0,1, -1,0,1, -1,0,1};
      float klv[26], dst[26];
      float s = 0.f;
#pragma unroll
      for (int t = 0; t < 26; t++) {
        const int nd = dd + DI[t], nh = hh + DJ[t], nw = ww + DK[t];
        const bool inb = ((unsigned)nd < (unsigned)D_) && ((unsigned)nh < (unsigned)H_) &&
                         ((unsigned)nw < (unsigned)W_);
        const int nidx = (nd * H_ + nh) * W_ + nw;
        dst[t] = inb ? gdist[nidx] : 0.f;
        // coordinate masks from the reference's (batch,d,h) indexing bug, specialized to B=1:
        //  i==+1 -> 0; j==+1 -> 0; j==-1 -> only d==0; k==+1 -> only h==159; k==-1 -> only h==0
        bool keep;
        if (DI[t] == 1 || DJ[t] == 1) keep = false;
        else {
          keep = true;
          if (DJ[t] == -1) keep = (dd == 0);
          if (DK[t] == 1) keep = keep && (hh == H_ - 1);
          if (DK[t] == -1) keep = keep && (hh == 0);
        }
        float kt = 0.f;
        if (keep) {
          float t0 = 0.f, t1 = 0.f;
          if (inb) { t0 = inp[nidx]; t1 = inp[N_ + nidx]; }
          const float a0 = (t0 > 0.f) ? t0 * logf(t0) : 0.f;
          const float a1 = (t1 > 0.f) ? t1 * logf(t1) : 0.f;
          const float kldm = 0.5f * ((a0 - t0 * p0) + (a1 - t1 * p1));
          kt = expf(kldm);
        }
        klv[t] = kt;
        s += kt;
      }
      const float denom = (s == 0.f) ? 1.f : s;
      int amin = 0;
      float dmin = dst[0];
#pragma unroll
      for (int t = 1; t < 26; t++) {
        if (dst[t] < dmin) { dmin = dst[t]; amin = t; }  // first-min, like jnp.argmin
      }
      const float yoff = (float)(0.2 / 26.0);
      float bsum = 0.f;
#pragma unroll
      for (int t = 0; t < 26; t++) {
        const float x = klv[t] / denom;
        const float y = (t == amin) ? 0.8f : yoff;
        bsum += fmaxf(x, 0.f) - x * y + log1pf(expf(-fabsf(x)));
      }
      myloss = (fminf(g, 20.f) / 20.f) * (bsum / 26.f);
    }
  }
  __shared__ float ls[256];
  __shared__ unsigned lc[256];
  ls[tid] = myloss;
  lc[tid] = mycnt;
  __syncthreads();
  for (int o = 128; o > 0; o >>= 1) {
    if (tid < o) { ls[tid] += ls[tid + o]; lc[tid] += lc[tid + o]; }
    __syncthreads();
  }
  if (tid == 0) { psum[blockIdx.x] = ls[0]; pcnt[blockIdx.x] = lc[0]; }
}

// ---------------- deterministic final reduce (1 block) ----------------
__global__ __launch_bounds__(256) void k_reduce(const float* __restrict__ psum,
                                                const unsigned* __restrict__ pcnt,
                                                float* __restrict__ out) {
  __shared__ float ls[256];
  __shared__ unsigned lc[256];
  const int t = threadIdx.x;
  float s = 0.f;
  unsigned c = 0;
  for (int i = t; i < NBLK; i += 256) { s += psum[i]; c += pcnt[i]; }
  ls[t] = s;
  lc[t] = c;
  __syncthreads();
  for (int o = 128; o > 0; o >>= 1) {
    if (t < o) { ls[t] += ls[t + o]; lc[t] += lc[t + o]; }
    __syncthreads();
  }
  if (t == 0) out[0] = ls[0] / (float)lc[0];
}

extern "C" void kernel_launch(void* const* d_in, const int* in_sizes, int n_in,
                              void* d_out, int out_size, void* d_ws, size_t ws_size,
                              hipStream_t stream) {
  (void)in_sizes; (void)n_in; (void)out_size; (void)ws_size;
  const float* inp = (const float*)d_in[0];
  const int* tgt = (const int*)d_in[1];
  float* out = (float*)d_out;
  char* ws = (char*)d_ws;

  float* kl = (float*)(ws + OFF_KL);
  float* fA = (float*)(ws + OFF_FA);
  float* fB = (float*)(ws + OFF_FB);
  unsigned* cand = (unsigned*)(ws + OFF_CAND);
  unsigned* g1 = (unsigned*)(ws + OFF_G1);
  unsigned* sc = (unsigned*)(ws + OFF_SC);
  float* ps = (float*)(ws + OFF_PS);
  unsigned* pc = (unsigned*)(ws + OFF_PC);

  k_zero<<<17, 256, 0, stream>>>(g1, sc);
  k_prep<<<HBLK, 256, 0, stream>>>(inp, tgt, kl, fA, g1);
  k_dt_d<<<NBLK, 256, 0, stream>>>(fA, fB);             // EDT axis D
  k_dt_h<<<NBLK, 256, 0, stream>>>(fB, fA, g1, sc);     // EDT axis H + sel1 (block 0)
  k_dt_w<<<NBLK, 256, 0, stream>>>(fA, fB, kl, cand, sc); // EDT axis W + sqrt + compaction
  k_sel23<<<1, 256, 0, stream>>>(cand, sc);             // thr = order statistic
  k_loss<<<NBLK, 256, 0, stream>>>(inp, kl, fB, sc, ps, pc);
  k_reduce<<<1, 256, 0, stream>>>(ps, pc, out);
}

// Round 5
// 90.329 us; speedup vs baseline: 5.4480x; 1.2695x over previous
//
#include <hip/hip_runtime.h>
#include <math.h>

// Problem dims (fixed by setup_inputs): inp [1,2,48,160,160] f32, target [1,48,160,160] i32
#define D_ 48
#define H_ 160
#define W_ 160
#define HW_ 25600
#define N_ 1228800
#define NBLK 4800          // N_/256
#define HBLK 600           // 8 elems/thread passes
#define K1_ 1216512u       // 1-based rank of sorted index floor(0.99*(N-1)); frac==0 in f32 (R1: absmax 0.0)

static_assert(N_ == D_ * HW_, "dims");
static_assert(N_ == NBLK * 256, "grid");
static_assert(N_ == HBLK * 256 * 8, "hist grid");

// ---- workspace layout (bytes) ----
#define OFF_KL   0u
#define OFF_FA   (N_ * 4u)
#define OFF_FB   (2u * N_ * 4u)
#define OFF_CAND (3u * N_ * 4u)            // worst-case capacity: all N values in one bucket
#define OFF_G1   (4u * N_ * 4u)            // 4096 u32
#define OFF_SC   (OFF_G1 + 4096u * 4u)     // 16 u32 scalars
#define OFF_PS   (OFF_SC + 64u)
#define OFF_PC   (OFF_PS + NBLK * 4u)
// sc: [0]=b1 [1]=rank-in-bucket [6]=thr bits [8]=candCount

__device__ __forceinline__ unsigned fkey(float v) {
  unsigned u = __float_as_uint(v);
  return (u & 0x80000000u) ? ~u : (u | 0x80000000u);  // monotone map: float asc -> uint asc
}

// ---------------- zero g1 + scalars ----------------
__global__ __launch_bounds__(256) void k_zero(unsigned* __restrict__ g1,
                                              unsigned* __restrict__ sc) {
  const int i = blockIdx.x * 256 + threadIdx.x;
  if (i < 4096) g1[i] = 0u;
  else if (i < 4112) sc[i - 4096] = 0u;
}

// ---------------- kl_vals + initial dist field + level-1 (hi-12) histogram ----------------
__global__ __launch_bounds__(256) void k_prep(const float* __restrict__ inp,
                                              const int* __restrict__ tgt,
                                              float* __restrict__ kl,
                                              float* __restrict__ f0,
                                              unsigned* __restrict__ ghist) {
  __shared__ unsigned h[4096];
  const int tid = threadIdx.x;
  for (int i = tid; i < 4096; i += 256) h[i] = 0;
  __syncthreads();
  const int base = blockIdx.x * 2048;
  for (int e = 0; e < 8; e++) {
    const int idx = base + e * 256 + tid;
    const int ww = idx % W_;
    const int hh = (idx / W_) % H_;
    const int dd = idx / HW_;
    const float p0 = inp[idx];
    const float p1 = inp[N_ + idx];

    float klh = -1.0f, klv = -1.0f, kld = -1.0f;
    if (ww < W_ - 1) {
      const float t0 = inp[idx + 1], t1 = inp[N_ + idx + 1];
      const float a0 = (t0 > 0.f) ? t0 * logf(t0) : 0.f;
      const float a1 = (t1 > 0.f) ? t1 * logf(t1) : 0.f;
      klh = 0.5f * ((a0 - t0 * p0) + (a1 - t1 * p1));
    }
    if (hh < H_ - 1) {
      const float t0 = inp[idx + W_], t1 = inp[N_ + idx + W_];
      const float a0 = (t0 > 0.f) ? t0 * logf(t0) : 0.f;
      const float a1 = (t1 > 0.f) ? t1 * logf(t1) : 0.f;
      klv = 0.5f * ((a0 - t0 * p0) + (a1 - t1 * p1));
    }
    if (dd < D_ - 1) {
      const float t0 = inp[idx + HW_], t1 = inp[N_ + idx + HW_];
      const float a0 = (t0 > 0.f) ? t0 * logf(t0) : 0.f;
      const float a1 = (t1 > 0.f) ? t1 * logf(t1) : 0.f;
      kld = 0.5f * ((a0 - t0 * p0) + (a1 - t1 * p1));
    }
    const float kmax = fmaxf(fmaxf(klh, klv), kld);
    kl[idx] = kmax;
    atomicAdd(&h[fkey(kmax) >> 20], 1u);

    const int tv = tgt[idx];
    const int t1 = (ww < W_ - 1) ? tgt[idx + 1] : 0;
    const int t2 = (hh < H_ - 1) ? tgt[idx + W_] : 0;
    const int t3 = (dd < D_ - 1) ? tgt[idx + HW_] : 0;
    f0[idx] = (3 * tv != t1 + t2 + t3) ? 0.f : 1e10f;
  }
  __syncthreads();
  for (int i = tid; i < 4096; i += 256) {
    const unsigned c = h[i];
    if (c) atomicAdd(&ghist[i], c);
  }
}

// ---------------- EDT pass along D, early-exit outward scan (bit-exact vs brute force) ----------------
__global__ __launch_bounds__(256) void k_dt_d(const float* __restrict__ fin,
                                              float* __restrict__ fout) {
  const int idx = blockIdx.x * 256 + threadIdx.x;
  const int pos = idx / HW_;
  float m = fin[idx];
  for (int r = 1; r < D_; r++) {
    const float r2 = (float)(r * r);
    if (r2 >= m) break;
    const bool okm = (pos - r >= 0), okp = (pos + r < D_);
    if (!okm && !okp) break;
    if (okm) m = fminf(m, fin[idx - r * HW_] + r2);
    if (okp) m = fminf(m, fin[idx + r * HW_] + r2);
  }
  fout[idx] = m;
}

// ---------------- EDT pass along H + level-1 rank-select in block 0 (g1 boundary-synced) ----------------
__global__ __launch_bounds__(256) void k_dt_h(const float* __restrict__ fin,
                                              float* __restrict__ fout,
                                              const unsigned* __restrict__ g1,
                                              unsigned* __restrict__ sc) {
  const int idx = blockIdx.x * 256 + threadIdx.x;
  const int pos = (idx / W_) % H_;
  float m = fin[idx];
  for (int r = 1; r < H_; r++) {
    const float r2 = (float)(r * r);
    if (r2 >= m) break;
    const bool okm = (pos - r >= 0), okp = (pos + r < H_);
    if (!okm && !okp) break;
    if (okm) m = fminf(m, fin[idx - r * W_] + r2);
    if (okp) m = fminf(m, fin[idx + r * W_] + r2);
  }
  fout[idx] = m;

  if (blockIdx.x == 0) {
    __shared__ unsigned ssum[256];
    const int t = threadIdx.x;
    unsigned s = 0;
#pragma unroll
    for (int i = 0; i < 16; i++) s += g1[t * 16 + i];
    const unsigned mine = s;
    ssum[t] = s;
    __syncthreads();
    // Hillis-Steele inclusive scan (replaces 256-iteration serial loop)
    for (int o = 1; o < 256; o <<= 1) {
      const unsigned add = (t >= o) ? ssum[t - o] : 0u;
      __syncthreads();
      ssum[t] += add;
      __syncthreads();
    }
    const unsigned before = ssum[t] - mine;
    if (before < K1_ && K1_ <= before + mine) {
      unsigned cum = before;
      for (int i = 0; i < 16; i++) {
        const unsigned c = g1[t * 16 + i];
        if (cum < K1_ && K1_ <= cum + c) { sc[0] = (unsigned)(t * 16 + i); sc[1] = K1_ - cum; break; }
        cum += c;
      }
    }
  }
}

// ---------------- EDT along W + sqrt + block-aggregated bucket-b1 compaction ----------------
// 600 blocks x 8 voxels/thread. One global atomic per block (<=600 total) instead of one per
// candidate (~12K serialized same-address RMWs -> the R4 regression).
__global__ __launch_bounds__(256) void k_dt_w(const float* __restrict__ fin,
                                              float* __restrict__ fout,
                                              const float* __restrict__ kl,
                                              unsigned* __restrict__ cand,
                                              unsigned* __restrict__ sc) {
  const int tid = threadIdx.x;
  const int base = blockIdx.x * 2048;
  const unsigned b1 = sc[0];
  unsigned keys[8];
  int cnt = 0;
  for (int e = 0; e < 8; e++) {
    const int idx = base + e * 256 + tid;
    const int pos = idx % W_;
    float m = fin[idx];
    for (int r = 1; r < W_; r++) {
      const float r2 = (float)(r * r);
      if (r2 >= m) break;
      const bool okm = (pos - r >= 0), okp = (pos + r < W_);
      if (!okm && !okp) break;
      if (okm) m = fminf(m, fin[idx - r] + r2);
      if (okp) m = fminf(m, fin[idx + r] + r2);
    }
    fout[idx] = sqrtf(m);
    const unsigned key = fkey(kl[idx]);
    if ((key >> 20) == b1) { keys[cnt] = key & 0xFFFFFu; cnt++; }
  }
  __shared__ unsigned scnt[256];
  __shared__ unsigned sbase;
  scnt[tid] = (unsigned)cnt;
  __syncthreads();
  for (int o = 1; o < 256; o <<= 1) {
    const unsigned add = (tid >= o) ? scnt[tid - o] : 0u;
    __syncthreads();
    scnt[tid] += add;
    __syncthreads();
  }
  if (tid == 255 && scnt[255] > 0) sbase = atomicAdd(&sc[8], scnt[255]);
  __syncthreads();
  if (cnt) {
    const unsigned wb = sbase + scnt[tid] - (unsigned)cnt;
    for (int i = 0; i < cnt; i++) cand[wb + i] = keys[i];
  }
}

// ---------------- 12+8 radix select over the compacted candidates (1 block) ----------------
__global__ __launch_bounds__(256) void k_sel23(const unsigned* __restrict__ cand,
                                               unsigned* __restrict__ sc) {
  const int tid = threadIdx.x;
  const unsigned M = sc[8];
  const unsigned K = sc[1];
  __shared__ unsigned hist[4096];
  __shared__ unsigned ssum[256];
  __shared__ unsigned sBA, sKB;
  for (int i = tid; i < 4096; i += 256) hist[i] = 0;
  __syncthreads();
  const unsigned M4 = M & ~3u;
  for (unsigned g = (unsigned)tid; g * 4u < M4; g += 256u) {
    const uint4 v = *reinterpret_cast<const uint4*>(&cand[g * 4u]);
    atomicAdd(&hist[(v.x >> 8) & 0xFFFu], 1u);
    atomicAdd(&hist[(v.y >> 8) & 0xFFFu], 1u);
    atomicAdd(&hist[(v.z >> 8) & 0xFFFu], 1u);
    atomicAdd(&hist[(v.w >> 8) & 0xFFFu], 1u);
  }
  for (unsigned i = M4 + (unsigned)tid; i < M; i += 256u) atomicAdd(&hist[(cand[i] >> 8) & 0xFFFu], 1u);
  __syncthreads();
  unsigned mine = 0;
#pragma unroll
  for (int i = 0; i < 16; i++) mine += hist[tid * 16 + i];
  ssum[tid] = mine;
  __syncthreads();
  for (int o = 1; o < 256; o <<= 1) {
    const unsigned add = (tid >= o) ? ssum[tid - o] : 0u;
    __syncthreads();
    ssum[tid] += add;
    __syncthreads();
  }
  {
    const unsigned before = ssum[tid] - mine;
    if (before < K && K <= before + mine) {
      unsigned cum = before;
      for (int i = 0; i < 16; i++) {
        const unsigned c = hist[tid * 16 + i];
        if (cum < K && K <= cum + c) { sBA = (unsigned)(tid * 16 + i); sKB = K - cum; break; }
        cum += c;
      }
    }
  }
  __syncthreads();
  const unsigned bA = sBA, KB = sKB;
  __shared__ unsigned h2[256];
  h2[tid] = 0;
  __syncthreads();
  for (unsigned g = (unsigned)tid; g * 4u < M4; g += 256u) {
    const uint4 v = *reinterpret_cast<const uint4*>(&cand[g * 4u]);
    if (((v.x >> 8) & 0xFFFu) == bA) atomicAdd(&h2[v.x & 0xFFu], 1u);
    if (((v.y >> 8) & 0xFFFu) == bA) atomicAdd(&h2[v.y & 0xFFu], 1u);
    if (((v.z >> 8) & 0xFFFu) == bA) atomicAdd(&h2[v.z & 0xFFu], 1u);
    if (((v.w >> 8) & 0xFFFu) == bA) atomicAdd(&h2[v.w & 0xFFu], 1u);
  }
  for (unsigned i = M4 + (unsigned)tid; i < M; i += 256u) {
    const unsigned v = cand[i];
    if (((v >> 8) & 0xFFFu) == bA) atomicAdd(&h2[v & 0xFFu], 1u);
  }
  __syncthreads();
  const unsigned mine2 = h2[tid];
  ssum[tid] = mine2;
  __syncthreads();
  for (int o = 1; o < 256; o <<= 1) {
    const unsigned add = (tid >= o) ? ssum[tid - o] : 0u;
    __syncthreads();
    ssum[tid] += add;
    __syncthreads();
  }
  {
    const unsigned before = ssum[tid] - mine2;
    if (before < KB && KB <= before + mine2) {
      const unsigned key = (sc[0] << 20) | (bA << 8) | (unsigned)tid;
      sc[6] = (key & 0x80000000u) ? (key & 0x7FFFFFFFu) : ~key;  // inverse of fkey
    }
  }
}

// ---------------- masked loss at each voxel + block partials (plain stores) ----------------
__global__ __launch_bounds__(256) void k_loss(const float* __restrict__ inp,
                                              const float* __restrict__ kl,
                                              const float* __restrict__ gdist,
                                              const unsigned* __restrict__ sc,
                                              float* __restrict__ psum,
                                              unsigned* __restrict__ pcnt) {
  const int tid = threadIdx.x;
  const int idx = blockIdx.x * 256 + tid;
  const float thr = __uint_as_float(sc[6]);
  float myloss = 0.f;
  unsigned mycnt = 0u;
  if (kl[idx] >= thr) {
    mycnt = 1u;
    const float g = gdist[idx];
    if (g != 0.f) {
      const int ww = idx % W_;
      const int hh = (idx / W_) % H_;
      const int dd = idx / HW_;
      const float p0 = inp[idx];
      const float p1 = inp[N_ + idx];
      // DIRECTIONS in torch-loop order: i outer, j mid, k inner, skipping (0,0,0)
      constexpr int DI[26] = {-1,-1,-1,-1,-1,-1,-1,-1,-1, 0,0,0,0,0,0,0,0, 1,1,1,1,1,1,1,1,1};
      constexpr int DJ[26] = {-1,-1,-1, 0,0,0, 1,1,1, -1,-1,-1, 0,0, 1,1,1, -1,-1,-1, 0,0,0, 1,1,1};
      constexpr int DK[26] = {-1,0,1, -1,0,1, -1,0,1, -1,0,1, -1,1, -1,0,1, -1,0,1, -1,0,1, -1,0,1};
      float klv[26], dst[26];
      float s = 0.f;
#pragma unroll
      for (int t = 0; t < 26; t++) {
        const int nd = dd + DI[t], nh = hh + DJ[t], nw = ww + DK[t];
        const bool inb = ((unsigned)nd < (unsigned)D_) && ((unsigned)nh < (unsigned)H_) &&
                         ((unsigned)nw < (unsigned)W_);
        const int nidx = (nd * H_ + nh) * W_ + nw;
        dst[t] = inb ? gdist[nidx] : 0.f;
        // coordinate masks from the reference's (batch,d,h) indexing bug, specialized to B=1:
        //  i==+1 -> 0; j==+1 -> 0; j==-1 -> only d==0; k==+1 -> only h==159; k==-1 -> only h==0
        bool keep;
        if (DI[t] == 1 || DJ[t] == 1) keep = false;
        else {
          keep = true;
          if (DJ[t] == -1) keep = (dd == 0);
          if (DK[t] == 1) keep = keep && (hh == H_ - 1);
          if (DK[t] == -1) keep = keep && (hh == 0);
        }
        float kt = 0.f;
        if (keep) {
          float t0 = 0.f, t1 = 0.f;
          if (inb) { t0 = inp[nidx]; t1 = inp[N_ + nidx]; }
          const float a0 = (t0 > 0.f) ? t0 * logf(t0) : 0.f;
          const float a1 = (t1 > 0.f) ? t1 * logf(t1) : 0.f;
          const float kldm = 0.5f * ((a0 - t0 * p0) + (a1 - t1 * p1));
          kt = expf(kldm);
        }
        klv[t] = kt;
        s += kt;
      }
      const float denom = (s == 0.f) ? 1.f : s;
      int amin = 0;
      float dmin = dst[0];
#pragma unroll
      for (int t = 1; t < 26; t++) {
        if (dst[t] < dmin) { dmin = dst[t]; amin = t; }  // first-min, like jnp.argmin
      }
      const float yoff = (float)(0.2 / 26.0);
      float bsum = 0.f;
#pragma unroll
      for (int t = 0; t < 26; t++) {
        const float x = klv[t] / denom;
        const float y = (t == amin) ? 0.8f : yoff;
        bsum += fmaxf(x, 0.f) - x * y + log1pf(expf(-fabsf(x)));
      }
      myloss = (fminf(g, 20.f) / 20.f) * (bsum / 26.f);
    }
  }
  __shared__ float ls[256];
  __shared__ unsigned lc[256];
  ls[tid] = myloss;
  lc[tid] = mycnt;
  __syncthreads();
  for (int o = 128; o > 0; o >>= 1) {
    if (tid < o) { ls[tid] += ls[tid + o]; lc[tid] += lc[tid + o]; }
    __syncthreads();
  }
  if (tid == 0) { psum[blockIdx.x] = ls[0]; pcnt[blockIdx.x] = lc[0]; }
}

// ---------------- deterministic final reduce (1 block, vectorized) ----------------
__global__ __launch_bounds__(256) void k_reduce(const float* __restrict__ psum,
                                                const unsigned* __restrict__ pcnt,
                                                float* __restrict__ out) {
  __shared__ float ls[256];
  __shared__ unsigned lc[256];
  const int t = threadIdx.x;
  float s = 0.f;
  unsigned c = 0;
  for (int g = t; g * 4 < NBLK; g += 256) {
    const float4 s4 = *reinterpret_cast<const float4*>(&psum[g * 4]);
    const uint4 c4 = *reinterpret_cast<const uint4*>(&pcnt[g * 4]);
    s += (s4.x + s4.y) + (s4.z + s4.w);
    c += c4.x + c4.y + c4.z + c4.w;
  }
  ls[t] = s;
  lc[t] = c;
  __syncthreads();
  for (int o = 128; o > 0; o >>= 1) {
    if (t < o) { ls[t] += ls[t + o]; lc[t] += lc[t + o]; }
    __syncthreads();
  }
  if (t == 0) out[0] = ls[0] / (float)lc[0];
}

extern "C" void kernel_launch(void* const* d_in, const int* in_sizes, int n_in,
                              void* d_out, int out_size, void* d_ws, size_t ws_size,
                              hipStream_t stream) {
  (void)in_sizes; (void)n_in; (void)out_size; (void)ws_size;
  const float* inp = (const float*)d_in[0];
  const int* tgt = (const int*)d_in[1];
  float* out = (float*)d_out;
  char* ws = (char*)d_ws;

  float* kl = (float*)(ws + OFF_KL);
  float* fA = (float*)(ws + OFF_FA);
  float* fB = (float*)(ws + OFF_FB);
  unsigned* cand = (unsigned*)(ws + OFF_CAND);
  unsigned* g1 = (unsigned*)(ws + OFF_G1);
  unsigned* sc = (unsigned*)(ws + OFF_SC);
  float* ps = (float*)(ws + OFF_PS);
  unsigned* pc = (unsigned*)(ws + OFF_PC);

  k_zero<<<17, 256, 0, stream>>>(g1, sc);
  k_prep<<<HBLK, 256, 0, stream>>>(inp, tgt, kl, fA, g1);
  k_dt_d<<<NBLK, 256, 0, stream>>>(fA, fB);               // EDT axis D
  k_dt_h<<<NBLK, 256, 0, stream>>>(fB, fA, g1, sc);       // EDT axis H + sel1 (block 0)
  k_dt_w<<<HBLK, 256, 0, stream>>>(fA, fB, kl, cand, sc); // EDT axis W + sqrt + aggregated compaction
  k_sel23<<<1, 256, 0, stream>>>(cand, sc);               // thr = order statistic
  k_loss<<<NBLK, 256, 0, stream>>>(inp, kl, fB, sc, ps, pc);
  k_reduce<<<1, 256, 0, stream>>>(ps, pc, out);
}

// Round 6
// 86.409 us; speedup vs baseline: 5.6951x; 1.0454x over previous
//
#include <hip/hip_runtime.h>
#include <math.h>

// Problem dims (fixed by setup_inputs): inp [1,2,48,160,160] f32, target [1,48,160,160] i32
#define D_ 48
#define H_ 160
#define W_ 160
#define HW_ 25600
#define N_ 1228800
#define NBLK 4800          // N_/256
#define HBLK 600           // 8 elems/thread passes
#define K1_ 1216512u       // 1-based rank of sorted index floor(0.99*(N-1)); frac==0 in f32 (R1: absmax 0.0)

static_assert(N_ == D_ * HW_, "dims");
static_assert(N_ == NBLK * 256, "grid");
static_assert(N_ == HBLK * 256 * 8, "hist grid");

// ---- workspace layout (bytes) ----
#define OFF_KL   0u
#define OFF_FA   (N_ * 4u)
#define OFF_FB   (2u * N_ * 4u)
#define OFF_CAND (3u * N_ * 4u)            // worst-case capacity: all N values in one bucket
#define OFF_G1   (4u * N_ * 4u)            // 4096 u32
#define OFF_SC   (OFF_G1 + 4096u * 4u)     // 16 u32 scalars
#define OFF_PS   (OFF_SC + 64u)
#define OFF_PC   (OFF_PS + NBLK * 4u)
// sc: [0]=b1 [1]=rank-in-bucket [6]=thr bits [8]=candCount

__device__ __forceinline__ unsigned fkey(float v) {
  unsigned u = __float_as_uint(v);
  return (u & 0x80000000u) ? ~u : (u | 0x80000000u);  // monotone map: float asc -> uint asc
}

// ---------------- zero g1 + scalars ----------------
__global__ __launch_bounds__(256) void k_zero(unsigned* __restrict__ g1,
                                              unsigned* __restrict__ sc) {
  const int i = blockIdx.x * 256 + threadIdx.x;
  if (i < 4096) g1[i] = 0u;
  else if (i < 4112) sc[i - 4096] = 0u;
}

// ---------------- kl_vals + initial dist field + level-1 (hi-12) histogram ----------------
__global__ __launch_bounds__(256) void k_prep(const float* __restrict__ inp,
                                              const int* __restrict__ tgt,
                                              float* __restrict__ kl,
                                              float* __restrict__ f0,
                                              unsigned* __restrict__ ghist) {
  __shared__ unsigned h[4096];
  const int tid = threadIdx.x;
  for (int i = tid; i < 4096; i += 256) h[i] = 0;
  __syncthreads();
  const int base = blockIdx.x * 2048;
  for (int e = 0; e < 8; e++) {
    const int idx = base + e * 256 + tid;
    const int ww = idx % W_;
    const int hh = (idx / W_) % H_;
    const int dd = idx / HW_;
    const float p0 = inp[idx];
    const float p1 = inp[N_ + idx];

    float klh = -1.0f, klv = -1.0f, kld = -1.0f;
    if (ww < W_ - 1) {
      const float t0 = inp[idx + 1], t1 = inp[N_ + idx + 1];
      const float a0 = (t0 > 0.f) ? t0 * logf(t0) : 0.f;
      const float a1 = (t1 > 0.f) ? t1 * logf(t1) : 0.f;
      klh = 0.5f * ((a0 - t0 * p0) + (a1 - t1 * p1));
    }
    if (hh < H_ - 1) {
      const float t0 = inp[idx + W_], t1 = inp[N_ + idx + W_];
      const float a0 = (t0 > 0.f) ? t0 * logf(t0) : 0.f;
      const float a1 = (t1 > 0.f) ? t1 * logf(t1) : 0.f;
      klv = 0.5f * ((a0 - t0 * p0) + (a1 - t1 * p1));
    }
    if (dd < D_ - 1) {
      const float t0 = inp[idx + HW_], t1 = inp[N_ + idx + HW_];
      const float a0 = (t0 > 0.f) ? t0 * logf(t0) : 0.f;
      const float a1 = (t1 > 0.f) ? t1 * logf(t1) : 0.f;
      kld = 0.5f * ((a0 - t0 * p0) + (a1 - t1 * p1));
    }
    const float kmax = fmaxf(fmaxf(klh, klv), kld);
    kl[idx] = kmax;
    atomicAdd(&h[fkey(kmax) >> 20], 1u);

    const int tv = tgt[idx];
    const int t1 = (ww < W_ - 1) ? tgt[idx + 1] : 0;
    const int t2 = (hh < H_ - 1) ? tgt[idx + W_] : 0;
    const int t3 = (dd < D_ - 1) ? tgt[idx + HW_] : 0;
    f0[idx] = (3 * tv != t1 + t2 + t3) ? 0.f : 1e10f;
  }
  __syncthreads();
  for (int i = tid; i < 4096; i += 256) {
    const unsigned c = h[i];
    if (c) atomicAdd(&ghist[i], c);
  }
}

// ---------------- EDT pass along D + level-1 rank-select in block 0 (g1 boundary-synced) ----------------
// Early-exit scan is bit-exact vs brute force: f>=0 => RN(f[j]+r^2) >= r^2, so once r^2 >= m no
// candidate can lower the min; min over a set is order-independent.
__global__ __launch_bounds__(256) void k_dt_d(const float* __restrict__ fin,
                                              float* __restrict__ fout,
                                              const unsigned* __restrict__ g1,
                                              unsigned* __restrict__ sc) {
  const int idx = blockIdx.x * 256 + threadIdx.x;
  const int pos = idx / HW_;
  float m = fin[idx];
  for (int r = 1; r < D_; r++) {
    const float r2 = (float)(r * r);
    if (r2 >= m) break;
    const bool okm = (pos - r >= 0), okp = (pos + r < D_);
    if (!okm && !okp) break;
    if (okm) m = fminf(m, fin[idx - r * HW_] + r2);
    if (okp) m = fminf(m, fin[idx + r * HW_] + r2);
  }
  fout[idx] = m;

  if (blockIdx.x == 0) {
    __shared__ unsigned ssum[256];
    const int t = threadIdx.x;
    unsigned s = 0;
#pragma unroll
    for (int i = 0; i < 16; i++) s += g1[t * 16 + i];
    const unsigned mine = s;
    ssum[t] = s;
    __syncthreads();
    for (int o = 1; o < 256; o <<= 1) {
      const unsigned add = (t >= o) ? ssum[t - o] : 0u;
      __syncthreads();
      ssum[t] += add;
      __syncthreads();
    }
    const unsigned before = ssum[t] - mine;
    if (before < K1_ && K1_ <= before + mine) {
      unsigned cum = before;
      for (int i = 0; i < 16; i++) {
        const unsigned c = g1[t * 16 + i];
        if (cum < K1_ && K1_ <= cum + c) { sc[0] = (unsigned)(t * 16 + i); sc[1] = K1_ - cum; break; }
        cum += c;
      }
    }
  }
}

// ---------------- EDT along H (8/thr) + block-aggregated bucket-b1 compaction ----------------
// keys[] is indexed ONLY by the unrolled e => stays in VGPRs (no scratch). One global atomic
// per block (<=600). Candidate order nondeterministic; rank-select is order-independent.
__global__ __launch_bounds__(256) void k_dt_h(const float* __restrict__ fin,
                                              float* __restrict__ fout,
                                              const float* __restrict__ kl,
                                              unsigned* __restrict__ cand,
                                              unsigned* __restrict__ sc) {
  const int tid = threadIdx.x;
  const int base = blockIdx.x * 2048;
  const unsigned b1 = sc[0];
  unsigned keys[8];
  unsigned kmask = 0u;
#pragma unroll
  for (int e = 0; e < 8; e++) {
    const int idx = base + e * 256 + tid;
    const int pos = (idx / W_) % H_;
    float m = fin[idx];
    for (int r = 1; r < H_; r++) {
      const float r2 = (float)(r * r);
      if (r2 >= m) break;
      const bool okm = (pos - r >= 0), okp = (pos + r < H_);
      if (!okm && !okp) break;
      if (okm) m = fminf(m, fin[idx - r * W_] + r2);
      if (okp) m = fminf(m, fin[idx + r * W_] + r2);
    }
    fout[idx] = m;
    const unsigned key = fkey(kl[idx]);
    keys[e] = key & 0xFFFFFu;
    if ((key >> 20) == b1) kmask |= (1u << e);
  }
  const unsigned cnt = (unsigned)__popc(kmask);
  __shared__ unsigned scnt[256];
  __shared__ unsigned sbase;
  scnt[tid] = cnt;
  __syncthreads();
  for (int o = 1; o < 256; o <<= 1) {
    const unsigned add = (tid >= o) ? scnt[tid - o] : 0u;
    __syncthreads();
    scnt[tid] += add;
    __syncthreads();
  }
  if (tid == 255 && scnt[255] > 0) sbase = atomicAdd(&sc[8], scnt[255]);
  __syncthreads();
  if (cnt) {
    const unsigned wb = sbase + scnt[tid] - cnt;
#pragma unroll
    for (int e = 0; e < 8; e++) {
      if (kmask & (1u << e)) cand[wb + __popc(kmask & ((1u << e) - 1u))] = keys[e];
    }
  }
}

// ---------------- EDT along W + sqrt + 12+8 radix select over candidates in block 0 ----------------
__global__ __launch_bounds__(256) void k_dt_w(const float* __restrict__ fin,
                                              float* __restrict__ fout,
                                              const unsigned* __restrict__ cand,
                                              unsigned* __restrict__ sc) {
  const int idx = blockIdx.x * 256 + threadIdx.x;
  const int pos = idx % W_;
  float m = fin[idx];
  for (int r = 1; r < W_; r++) {
    const float r2 = (float)(r * r);
    if (r2 >= m) break;
    const bool okm = (pos - r >= 0), okp = (pos + r < W_);
    if (!okm && !okp) break;
    if (okm) m = fminf(m, fin[idx - r] + r2);
    if (okp) m = fminf(m, fin[idx + r] + r2);
  }
  fout[idx] = sqrtf(m);

  if (blockIdx.x != 0) return;
  // ---- block 0 tail: exact rank-select over compacted candidates (cand ready last kernel) ----
  const int tid = threadIdx.x;
  const unsigned M = sc[8];
  const unsigned K = sc[1];
  __shared__ unsigned hist[4096];
  __shared__ unsigned ssum[256];
  __shared__ unsigned sBA, sKB;
  for (int i = tid; i < 4096; i += 256) hist[i] = 0;
  __syncthreads();
  const unsigned M4 = M & ~3u;
  for (unsigned g = (unsigned)tid; g * 4u < M4; g += 256u) {
    const uint4 v = *reinterpret_cast<const uint4*>(&cand[g * 4u]);
    atomicAdd(&hist[(v.x >> 8) & 0xFFFu], 1u);
    atomicAdd(&hist[(v.y >> 8) & 0xFFFu], 1u);
    atomicAdd(&hist[(v.z >> 8) & 0xFFFu], 1u);
    atomicAdd(&hist[(v.w >> 8) & 0xFFFu], 1u);
  }
  for (unsigned i = M4 + (unsigned)tid; i < M; i += 256u) atomicAdd(&hist[(cand[i] >> 8) & 0xFFFu], 1u);
  __syncthreads();
  unsigned mine = 0;
#pragma unroll
  for (int i = 0; i < 16; i++) mine += hist[tid * 16 + i];
  ssum[tid] = mine;
  __syncthreads();
  for (int o = 1; o < 256; o <<= 1) {
    const unsigned add = (tid >= o) ? ssum[tid - o] : 0u;
    __syncthreads();
    ssum[tid] += add;
    __syncthreads();
  }
  {
    const unsigned before = ssum[tid] - mine;
    if (before < K && K <= before + mine) {
      unsigned cum = before;
      for (int i = 0; i < 16; i++) {
        const unsigned c = hist[tid * 16 + i];
        if (cum < K && K <= cum + c) { sBA = (unsigned)(tid * 16 + i); sKB = K - cum; break; }
        cum += c;
      }
    }
  }
  __syncthreads();
  const unsigned bA = sBA, KB = sKB;
  __shared__ unsigned h2[256];
  h2[tid] = 0;
  __syncthreads();
  for (unsigned g = (unsigned)tid; g * 4u < M4; g += 256u) {
    const uint4 v = *reinterpret_cast<const uint4*>(&cand[g * 4u]);
    if (((v.x >> 8) & 0xFFFu) == bA) atomicAdd(&h2[v.x & 0xFFu], 1u);
    if (((v.y >> 8) & 0xFFFu) == bA) atomicAdd(&h2[v.y & 0xFFu], 1u);
    if (((v.z >> 8) & 0xFFFu) == bA) atomicAdd(&h2[v.z & 0xFFu], 1u);
    if (((v.w >> 8) & 0xFFFu) == bA) atomicAdd(&h2[v.w & 0xFFu], 1u);
  }
  for (unsigned i = M4 + (unsigned)tid; i < M; i += 256u) {
    const unsigned v = cand[i];
    if (((v >> 8) & 0xFFFu) == bA) atomicAdd(&h2[v & 0xFFu], 1u);
  }
  __syncthreads();
  const unsigned mine2 = h2[tid];
  ssum[tid] = mine2;
  __syncthreads();
  for (int o = 1; o < 256; o <<= 1) {
    const unsigned add = (tid >= o) ? ssum[tid - o] : 0u;
    __syncthreads();
    ssum[tid] += add;
    __syncthreads();
  }
  {
    const unsigned before = ssum[tid] - mine2;
    if (before < KB && KB <= before + mine2) {
      const unsigned key = (sc[0] << 20) | (bA << 8) | (unsigned)tid;
      sc[6] = (key & 0x80000000u) ? (key & 0x7FFFFFFFu) : ~key;  // inverse of fkey
    }
  }
}

// ---------------- masked loss at each voxel + block partials (plain stores) ----------------
__global__ __launch_bounds__(256) void k_loss(const float* __restrict__ inp,
                                              const float* __restrict__ kl,
                                              const float* __restrict__ gdist,
                                              const unsigned* __restrict__ sc,
                                              float* __restrict__ psum,
                                              unsigned* __restrict__ pcnt) {
  const int tid = threadIdx.x;
  const int idx = blockIdx.x * 256 + tid;
  const float thr = __uint_as_float(sc[6]);
  float myloss = 0.f;
  unsigned mycnt = 0u;
  if (kl[idx] >= thr) {
    mycnt = 1u;
    const float g = gdist[idx];
    if (g != 0.f) {
      const int ww = idx % W_;
      const int hh = (idx / W_) % H_;
      const int dd = idx / HW_;
      const float p0 = inp[idx];
      const float p1 = inp[N_ + idx];
      // DIRECTIONS in torch-loop order: i outer, j mid, k inner, skipping (0,0,0)
      constexpr int DI[26] = {-1,-1,-1,-1,-1,-1,-1,-1,-1, 0,0,0,0,0,0,0,0, 1,1,1,1,1,1,1,1,1};
      constexpr int DJ[26] = {-1,-1,-1, 0,0,0, 1,1,1, -1,-1,-1, 0,0, 1,1,1, -1,-1,-1, 0,0,0, 1,1,1};
      constexpr int DK[26] = {-1,0,1, -1,0,1, -1,0,1, -1,0,1, -1,1, -1,0,1, -1,0,1, -1,0,1, -1,0,1};
      float klv[26], dst[26];
      float s = 0.f;
#pragma unroll
      for (int t = 0; t < 26; t++) {
        const int nd = dd + DI[t], nh = hh + DJ[t], nw = ww + DK[t];
        const bool inb = ((unsigned)nd < (unsigned)D_) && ((unsigned)nh < (unsigned)H_) &&
                         ((unsigned)nw < (unsigned)W_);
        const int nidx = (nd * H_ + nh) * W_ + nw;
        dst[t] = inb ? gdist[nidx] : 0.f;
        // coordinate masks from the reference's (batch,d,h) indexing bug, specialized to B=1:
        //  i==+1 -> 0; j==+1 -> 0; j==-1 -> only d==0; k==+1 -> only h==159; k==-1 -> only h==0
        bool keep;
        if (DI[t] == 1 || DJ[t] == 1) keep = false;
        else {
          keep = true;
          if (DJ[t] == -1) keep = (dd == 0);
          if (DK[t] == 1) keep = keep && (hh == H_ - 1);
          if (DK[t] == -1) keep = keep && (hh == 0);
        }
        float kt = 0.f;
        if (keep) {
          float t0 = 0.f, t1 = 0.f;
          if (inb) { t0 = inp[nidx]; t1 = inp[N_ + nidx]; }
          const float a0 = (t0 > 0.f) ? t0 * logf(t0) : 0.f;
          const float a1 = (t1 > 0.f) ? t1 * logf(t1) : 0.f;
          const float kldm = 0.5f * ((a0 - t0 * p0) + (a1 - t1 * p1));
          kt = expf(kldm);
        }
        klv[t] = kt;
        s += kt;
      }
      const float denom = (s == 0.f) ? 1.f : s;
      int amin = 0;
      float dmin = dst[0];
#pragma unroll
      for (int t = 1; t < 26; t++) {
        if (dst[t] < dmin) { dmin = dst[t]; amin = t; }  // first-min, like jnp.argmin
      }
      const float yoff = (float)(0.2 / 26.0);
      float bsum = 0.f;
#pragma unroll
      for (int t = 0; t < 26; t++) {
        const float x = klv[t] / denom;
        const float y = (t == amin) ? 0.8f : yoff;
        bsum += fmaxf(x, 0.f) - x * y + log1pf(expf(-fabsf(x)));
      }
      myloss = (fminf(g, 20.f) / 20.f) * (bsum / 26.f);
    }
  }
  __shared__ float ls[256];
  __shared__ unsigned lc[256];
  ls[tid] = myloss;
  lc[tid] = mycnt;
  __syncthreads();
  for (int o = 128; o > 0; o >>= 1) {
    if (tid < o) { ls[tid] += ls[tid + o]; lc[tid] += lc[tid + o]; }
    __syncthreads();
  }
  if (tid == 0) { psum[blockIdx.x] = ls[0]; pcnt[blockIdx.x] = lc[0]; }
}

// ---------------- deterministic final reduce (1 block, vectorized) ----------------
__global__ __launch_bounds__(256) void k_reduce(const float* __restrict__ psum,
                                                const unsigned* __restrict__ pcnt,
                                                float* __restrict__ out) {
  __shared__ float ls[256];
  __shared__ unsigned lc[256];
  const int t = threadIdx.x;
  float s = 0.f;
  unsigned c = 0;
  for (int g = t; g * 4 < NBLK; g += 256) {
    const float4 s4 = *reinterpret_cast<const float4*>(&psum[g * 4]);
    const uint4 c4 = *reinterpret_cast<const uint4*>(&pcnt[g * 4]);
    s += (s4.x + s4.y) + (s4.z + s4.w);
    c += c4.x + c4.y + c4.z + c4.w;
  }
  ls[t] = s;
  lc[t] = c;
  __syncthreads();
  for (int o = 128; o > 0; o >>= 1) {
    if (t < o) { ls[t] += ls[t + o]; lc[t] += lc[t + o]; }
    __syncthreads();
  }
  if (t == 0) out[0] = ls[0] / (float)lc[0];
}

extern "C" void kernel_launch(void* const* d_in, const int* in_sizes, int n_in,
                              void* d_out, int out_size, void* d_ws, size_t ws_size,
                              hipStream_t stream) {
  (void)in_sizes; (void)n_in; (void)out_size; (void)ws_size;
  const float* inp = (const float*)d_in[0];
  const int* tgt = (const int*)d_in[1];
  float* out = (float*)d_out;
  char* ws = (char*)d_ws;

  float* kl = (float*)(ws + OFF_KL);
  float* fA = (float*)(ws + OFF_FA);
  float* fB = (float*)(ws + OFF_FB);
  unsigned* cand = (unsigned*)(ws + OFF_CAND);
  unsigned* g1 = (unsigned*)(ws + OFF_G1);
  unsigned* sc = (unsigned*)(ws + OFF_SC);
  float* ps = (float*)(ws + OFF_PS);
  unsigned* pc = (unsigned*)(ws + OFF_PC);

  k_zero<<<17, 256, 0, stream>>>(g1, sc);
  k_prep<<<HBLK, 256, 0, stream>>>(inp, tgt, kl, fA, g1);
  k_dt_d<<<NBLK, 256, 0, stream>>>(fA, fB, g1, sc);        // EDT axis D + sel1 (block 0)
  k_dt_h<<<HBLK, 256, 0, stream>>>(fB, fA, kl, cand, sc);  // EDT axis H + aggregated compaction
  k_dt_w<<<NBLK, 256, 0, stream>>>(fA, fB, cand, sc);      // EDT axis W + sqrt + sel23 (block 0)
  k_loss<<<NBLK, 256, 0, stream>>>(inp, kl, fB, sc, ps, pc);
  k_reduce<<<1, 256, 0, stream>>>(ps, pc, out);
}